// Round 1
// baseline (1488.876 us; speedup 1.0000x reference)
//
#include <hip/hip_runtime.h>

#define S 32
#define KN 26
#define NLOC 3
#define NFUNC 14
#define NDIST 9
#define DTC 0.3f

__device__ __forceinline__ float frcp(float x) { return __builtin_amdgcn_rcpf(x); }

// tanh(x) = 1 - 2/(e^{2x}+1); exact saturation at +/-inf via exp->inf/0.
__device__ __forceinline__ float ftanh(float x) {
    float e = __expf(2.0f * x);
    return 1.0f - 2.0f * frcp(e + 1.0f);
}

// jax.nn.gelu(approximate=True): 0.5*x*(1+tanh(sqrt(2/pi)*(x+0.044715*x^3)))
__device__ __forceinline__ float fgelu(float x) {
    float t = ftanh(0.7978845608028654f * x * (1.0f + 0.044715f * x * x));
    return 0.5f * x * (1.0f + t);
}

// acc[j] += in[i] * W[(rowoff+i)*S + j], fully unrolled 32x32
#define MAT32(acc, inv, Wp, rowoff)                                  \
    _Pragma("unroll")                                                \
    for (int i_ = 0; i_ < S; i_++) {                                 \
        float a_ = (inv)[i_];                                        \
        _Pragma("unroll")                                            \
        for (int j_ = 0; j_ < S; j_++)                               \
            (acc)[j_] += a_ * (Wp)[((rowoff) + i_) * S + j_];        \
    }

__global__ __launch_bounds__(256, 1) void moe_kernel(
    const float* __restrict__ cs,  const float* __restrict__ nb,
    const float* __restrict__ Wl,  const float* __restrict__ bl,
    const float* __restrict__ Wm,  const float* __restrict__ bm,
    const float* __restrict__ Wu,  const float* __restrict__ bu,
    const float* __restrict__ Wc,  const float* __restrict__ bc,
    const float* __restrict__ Wd,  const float* __restrict__ bd,
    const float* __restrict__ lng, const float* __restrict__ lnb,
    const float* __restrict__ gW1, const float* __restrict__ gb1,
    const float* __restrict__ gW2, const float* __restrict__ gb2,
    float* __restrict__ out, int B)
{
    const int b = blockIdx.x * blockDim.x + threadIdx.x;
    if (b >= B) return;

    // ---- load current state x (8 x float4, row fully consumed)
    float x[S];
    {
        const float4* xp = reinterpret_cast<const float4*>(cs + (size_t)b * S);
        #pragma unroll
        for (int i = 0; i < S / 4; i++) {
            float4 v = xp[i];
            x[4*i+0] = v.x; x[4*i+1] = v.y; x[4*i+2] = v.z; x[4*i+3] = v.w;
        }
    }
    const float* nbp = nb + (size_t)b * (KN * S);

    float act[S];
    #pragma unroll
    for (int s = 0; s < S; s++) act[s] = 0.0f;

    // ---- local neighbors (rows 0..2) -> loc_agg
    float loc[S];
    {
        float rr[NLOC][S];
        #pragma unroll
        for (int k = 0; k < NLOC; k++) {
            const float4* rp = reinterpret_cast<const float4*>(nbp + k * S);
            #pragma unroll
            for (int i = 0; i < S / 4; i++) {
                float4 v = rp[i];
                rr[k][4*i+0] = v.x; rr[k][4*i+1] = v.y;
                rr[k][4*i+2] = v.z; rr[k][4*i+3] = v.w;
            }
        }
        #pragma unroll
        for (int s = 0; s < S; s++) {
            loc[s] = (rr[0][s] + rr[1][s] + rr[2][s]) * (1.0f / NLOC);
            act[s] += fabsf(rr[0][s]) + fabsf(rr[1][s]) + fabsf(rr[2][s]);
        }
    }

    // ---- y_local = x + tanh([x, loc_agg] @ Wl + bl)
    float yl[S];
    {
        float acc[S];
        #pragma unroll
        for (int j = 0; j < S; j++) acc[j] = bl[j];
        MAT32(acc, x, Wl, 0);
        MAT32(acc, loc, Wl, S);
        #pragma unroll
        for (int j = 0; j < S; j++) yl[j] = x[j] + ftanh(acc[j]);
    }

    // ---- func neighbors (rows 3..16): agg = sum gelu(row @ Wm + bm)
    float agg[S];
    #pragma unroll
    for (int j = 0; j < S; j++) agg[j] = 0.0f;
    {
        float4 cur[S / 4];
        {
            const float4* rp = reinterpret_cast<const float4*>(nbp + NLOC * S);
            #pragma unroll
            for (int i = 0; i < S / 4; i++) cur[i] = rp[i];
        }
        #pragma unroll 1
        for (int k = 0; k < NFUNC; k++) {
            // prefetch next row (double buffer: HBM latency hides under FMAs)
            float4 nxt[S / 4];
            #pragma unroll
            for (int i = 0; i < S / 4; i++) nxt[i] = cur[i];
            if (k + 1 < NFUNC) {
                const float4* np4 = reinterpret_cast<const float4*>(nbp + (NLOC + k + 1) * S);
                #pragma unroll
                for (int i = 0; i < S / 4; i++) nxt[i] = np4[i];
            }
            float r[S];
            #pragma unroll
            for (int i = 0; i < S / 4; i++) {
                r[4*i+0] = cur[i].x; r[4*i+1] = cur[i].y;
                r[4*i+2] = cur[i].z; r[4*i+3] = cur[i].w;
            }
            float tmp[S];
            #pragma unroll
            for (int j = 0; j < S; j++) tmp[j] = bm[j];
            MAT32(tmp, r, Wm, 0);
            #pragma unroll
            for (int j = 0; j < S; j++) agg[j] += fgelu(tmp[j]);
            #pragma unroll
            for (int s = 0; s < S; s++) act[s] += fabsf(r[s]);
            #pragma unroll
            for (int i = 0; i < S / 4; i++) cur[i] = nxt[i];
        }
    }

    // ---- h = x + tanh([x, agg/14] @ Wu + bu); y_func = h + DT*tanh(h @ Wc + bc)
    float yf[S];
    {
        float am[S];
        #pragma unroll
        for (int i = 0; i < S; i++) am[i] = agg[i] * (1.0f / NFUNC);
        float acc[S];
        #pragma unroll
        for (int j = 0; j < S; j++) acc[j] = bu[j];
        MAT32(acc, x, Wu, 0);
        MAT32(acc, am, Wu, S);
        float h[S];
        #pragma unroll
        for (int j = 0; j < S; j++) h[j] = x[j] + ftanh(acc[j]);
        float a2[S];
        #pragma unroll
        for (int j = 0; j < S; j++) a2[j] = bc[j];
        MAT32(a2, h, Wc, 0);
        #pragma unroll
        for (int j = 0; j < S; j++) yf[j] = h[j] + DTC * ftanh(a2[j]);
    }

    // ---- dist neighbors (rows 17..25) -> dist_agg (chunks of 3 rows)
    float dist[S];
    #pragma unroll
    for (int s = 0; s < S; s++) dist[s] = 0.0f;
    #pragma unroll 1
    for (int kk = 0; kk < 3; kk++) {
        float rr[3][S];
        #pragma unroll
        for (int k = 0; k < 3; k++) {
            const float4* rp = reinterpret_cast<const float4*>(nbp + (NLOC + NFUNC + 3 * kk + k) * S);
            #pragma unroll
            for (int i = 0; i < S / 4; i++) {
                float4 v = rp[i];
                rr[k][4*i+0] = v.x; rr[k][4*i+1] = v.y;
                rr[k][4*i+2] = v.z; rr[k][4*i+3] = v.w;
            }
        }
        #pragma unroll
        for (int s = 0; s < S; s++) {
            dist[s] += rr[0][s] + rr[1][s] + rr[2][s];
            act[s]  += fabsf(rr[0][s]) + fabsf(rr[1][s]) + fabsf(rr[2][s]);
        }
    }
    #pragma unroll
    for (int s = 0; s < S; s++) dist[s] *= (1.0f / NDIST);

    // ---- gate: softmax(gelu([layernorm(x), mean|nb|] @ gW1 + gb1) @ gW2 + gb2)
    float gate0, gate1, gate2;
    {
        float mu = 0.0f;
        #pragma unroll
        for (int s = 0; s < S; s++) mu += x[s];
        mu *= (1.0f / S);
        float var = 0.0f;
        #pragma unroll
        for (int s = 0; s < S; s++) { float d = x[s] - mu; var += d * d; }
        var *= (1.0f / S);
        float rstd = rsqrtf(var + 1e-5f);

        float g1[8];
        #pragma unroll
        for (int t = 0; t < 8; t++) g1[t] = gb1[t];
        #pragma unroll
        for (int i = 0; i < S; i++) {
            float a = (x[i] - mu) * rstd * lng[i] + lnb[i];
            #pragma unroll
            for (int t = 0; t < 8; t++) g1[t] += a * gW1[i * 8 + t];
        }
        #pragma unroll
        for (int i = 0; i < S; i++) {
            float a = act[i] * (1.0f / KN);
            #pragma unroll
            for (int t = 0; t < 8; t++) g1[t] += a * gW1[(S + i) * 8 + t];
        }
        float lg0 = gb2[0], lg1 = gb2[1], lg2 = gb2[2];
        #pragma unroll
        for (int t = 0; t < 8; t++) {
            float g = fgelu(g1[t]);
            lg0 += g * gW2[t * 3 + 0];
            lg1 += g * gW2[t * 3 + 1];
            lg2 += g * gW2[t * 3 + 2];
        }
        float mx = fmaxf(lg0, fmaxf(lg1, lg2));
        float e0 = __expf(lg0 - mx), e1 = __expf(lg1 - mx), e2 = __expf(lg2 - mx);
        float rs = frcp(e0 + e1 + e2);
        gate0 = e0 * rs; gate1 = e1 * rs; gate2 = e2 * rs;
    }

    // ---- combine local+func, then CNF (3 steps) for y_dist
    float comb[S];
    #pragma unroll
    for (int s = 0; s < S; s++) comb[s] = gate0 * yl[s] + gate1 * yf[s];

    float xt[S];
    #pragma unroll
    for (int s = 0; s < S; s++) xt[s] = x[s];
    #pragma unroll 1
    for (int it = 0; it < 3; it++) {
        float acc[S];
        #pragma unroll
        for (int j = 0; j < S; j++) acc[j] = bd[j];
        MAT32(acc, xt, Wd, 0);
        MAT32(acc, dist, Wd, S);
        #pragma unroll
        for (int j = 0; j < S; j++) xt[j] += DTC * ftanh(acc[j]);
    }
    #pragma unroll
    for (int s = 0; s < S; s++) comb[s] += gate2 * xt[s];

    // ---- store: combined (B,32) then gate (B,3)
    {
        float4* op = reinterpret_cast<float4*>(out + (size_t)b * S);
        #pragma unroll
        for (int i = 0; i < S / 4; i++)
            op[i] = make_float4(comb[4*i+0], comb[4*i+1], comb[4*i+2], comb[4*i+3]);
        float* gp = out + (size_t)B * S + (size_t)b * 3;
        gp[0] = gate0; gp[1] = gate1; gp[2] = gate2;
    }
}

extern "C" void kernel_launch(void* const* d_in, const int* in_sizes, int n_in,
                              void* d_out, int out_size, void* d_ws, size_t ws_size,
                              hipStream_t stream)
{
    const int B = in_sizes[0] / S;
    dim3 block(256);
    dim3 grid((B + 255) / 256);
    hipLaunchKernelGGL(moe_kernel, grid, block, 0, stream,
        (const float*)d_in[0],  (const float*)d_in[1],
        (const float*)d_in[2],  (const float*)d_in[3],
        (const float*)d_in[4],  (const float*)d_in[5],
        (const float*)d_in[6],  (const float*)d_in[7],
        (const float*)d_in[8],  (const float*)d_in[9],
        (const float*)d_in[10], (const float*)d_in[11],
        (const float*)d_in[12], (const float*)d_in[13],
        (const float*)d_in[14], (const float*)d_in[15],
        (const float*)d_in[16], (const float*)d_in[17],
        (float*)d_out, B);
}